// Round 6
// baseline (426.433 us; speedup 1.0000x reference)
//
#include <hip/hip_runtime.h>

#define NN 50000
#define NE 400000
#define SCAN_NB 196   // ceil(50000/256)

__global__ void k_hist(const int* __restrict__ rcv, int* __restrict__ cnt){
  int e = blockIdx.x*256 + threadIdx.x;
  if (e < NE) atomicAdd(&cnt[rcv[e]], 1);
}

__global__ void k_scanA(const int* __restrict__ cnt, int* __restrict__ bsum){
  __shared__ int sh[256];
  int i = blockIdx.x*256 + threadIdx.x;
  int v = (i < NN) ? cnt[i] : 0;
  sh[threadIdx.x] = v; __syncthreads();
  for (int off=128; off>0; off>>=1){
    if (threadIdx.x < off) sh[threadIdx.x] += sh[threadIdx.x+off];
    __syncthreads();
  }
  if (threadIdx.x==0) bsum[blockIdx.x] = sh[0];
}

__global__ void k_scanB(int* __restrict__ bsum){
  __shared__ int sh[256];
  int t = threadIdx.x;
  int v = (t < SCAN_NB) ? bsum[t] : 0;
  sh[t] = v; __syncthreads();
  for (int off=1; off<256; off<<=1){
    int x = (t>=off)? sh[t-off] : 0;
    __syncthreads();
    sh[t] += x;
    __syncthreads();
  }
  if (t < SCAN_NB) bsum[t] = sh[t] - v;   // exclusive
}

__global__ void k_scanC(const int* __restrict__ cnt, const int* __restrict__ bsum,
                        int* __restrict__ offs, int* __restrict__ cursor){
  __shared__ int sh[256];
  int t = threadIdx.x;
  int i = blockIdx.x*256 + t;
  int v = (i < NN) ? cnt[i] : 0;
  sh[t] = v; __syncthreads();
  for (int off=1; off<256; off<<=1){
    int x = (t>=off)? sh[t-off] : 0;
    __syncthreads();
    sh[t] += x;
    __syncthreads();
  }
  int excl = sh[t] - v + bsum[blockIdx.x];
  if (i < NN){ offs[i] = excl; cursor[i] = excl; }
}

__global__ void k_scatter(const int* __restrict__ rcv, const int* __restrict__ snd,
                          int* __restrict__ cursor, int* __restrict__ csr_snd){
  int e = blockIdx.x*256 + threadIdx.x;
  if (e < NE){
    int p = atomicAdd(&cursor[rcv[e]], 1);
    csr_snd[p] = snd[e];
  }
}

// Pack W0..W3 into float4 table: Wp[m*64+t] = {W0,W1,W2,W3}[m][t]
__global__ void k_prepW(const float* __restrict__ W0, const float* __restrict__ W1,
                        const float* __restrict__ W2, const float* __restrict__ W3,
                        float4* __restrict__ Wp){
  int i = blockIdx.x*256 + threadIdx.x;   // 0..2047
  if (i < 2048) Wp[i] = make_float4(W0[i], W1[i], W2[i], W3[i]);
}

// Aggregate A[n][m][k] = sum_edges feat[snd][m]*sh_k(edge). Wave-per-node,
// 2-wave blocks. SH staging padded to 80B/lane (20 dwords -> all 32 banks
// covered, no 4x write serialization). 10KB LDS -> 16 blocks/CU = 32 waves.
__global__ __launch_bounds__(128) void k_aggr2(
    const float* __restrict__ pos, const float* __restrict__ feat,
    const int* __restrict__ offs, const int* __restrict__ cnt,
    const int* __restrict__ csr_snd, float4* __restrict__ A4)
{
  __shared__ __align__(16) float smS[2][1280];   // 10 KB, stride 20/lane

  const int tid = threadIdx.x, wv = tid>>6, lane = tid&63;
  const int ml = lane&31, hh = lane>>5;
  const int n = blockIdx.x*2 + wv;          // 25000*2 == 50000
  const float pnx=pos[n*3], pny=pos[n*3+1], pnz=pos[n*3+2];
  const int start = offs[n], deg = cnt[n];
  const int nch = (deg+63)>>6;

  float acc[8];
  #pragma unroll
  for (int j=0;j<8;++j) acc[j]=0.f;

  const float SC3=1.7320508f, SC5=2.236068f, SC7=2.6457513f, SC15=3.8729833f,
              SC42=6.4807407f, SC70=8.3666003f, SC105=10.246951f;

  for (int c=0; c<nch; ++c){
    const int base = c<<6;
    int cn = deg - base; cn = (cn>64)?64:cn;     // >=1 inside loop
    int sE = 0;
    if (lane < cn){
      sE = csr_snd[start+base+lane];
      float rx = pnx - pos[sE*3];
      float ry = pny - pos[sE*3+1];
      float rz = pnz - pos[sE*3+2];
      float r = sqrtf(rx*rx+ry*ry+rz*rz);
      float inv = 1.0f/fmaxf(r,1e-12f);
      float x=rx*inv, y=ry*inv, z=rz*inv;
      float x2=x*x, y2=y*y, z2=z*z;
      float s1=SC3*x, s2=SC3*y, s3=SC3*z;
      float s4=SC15*x*y, s5=SC15*y*z, s6=0.5f*SC5*(3.f*z2-1.f), s7=SC15*x*z;
      float s8=0.5f*SC15*(x2-y2);
      float s9 =0.25f*SC70*y*(3.f*x2-y2);
      float s10=SC105*x*y*z;
      float s11=0.25f*SC42*y*(5.f*z2-1.f);
      float s12=0.5f*SC7*z*(5.f*z2-3.f);
      float s13=0.25f*SC42*x*(5.f*z2-1.f);
      float s14=0.5f*SC105*z*(x2-y2);
      float s15=0.25f*SC70*x*(x2-3.f*y2);
      float4* wp = (float4*)&smS[wv][lane*20];   // 80B slot, 16B-aligned
      wp[0] = make_float4(1.0f,s1,s2,s3);
      wp[1] = make_float4(s4,s5,s6,s7);
      wp[2] = make_float4(s8,s9,s10,s11);
      wp[3] = make_float4(s12,s13,s14,s15);
    }
    // same-wave LDS producer->consumer ordering (waves independent)
    asm volatile("s_waitcnt lgkmcnt(0)" ::: "memory");
    #pragma unroll 8
    for (int it=0; it<cn; ++it){
      int s = __builtin_amdgcn_readlane(sE, it);   // uniform sender id
      float f = feat[(size_t)s*32 + ml];           // 128B segment, L2-hot
      const float4* rp = (const float4*)&smS[wv][it*20 + hh*8];
      float4 q0=rp[0], q1=rp[1];                   // broadcast reads
      acc[0]+=f*q0.x; acc[1]+=f*q0.y; acc[2]+=f*q0.z; acc[3]+=f*q0.w;
      acc[4]+=f*q1.x; acc[5]+=f*q1.y; acc[6]+=f*q1.z; acc[7]+=f*q1.w;
    }
    asm volatile("" ::: "memory");  // reads before next chunk's overwrites
  }

  // A[n][m][k] row-major [m][16+k]: lane (ml,hh) owns m=ml, k=hh*8..hh*8+7
  float4* dst = A4 + (size_t)n*128 + ml*4 + hh*2;
  dst[0] = make_float4(acc[0],acc[1],acc[2],acc[3]);
  dst[1] = make_float4(acc[4],acc[5],acc[6],acc[7]);
}

// Transform: out[n][t][k] = sum_m A[n][m][k]*Wp[m][t].{class(k)} + self term.
// 1024 blocks x 512 thr (8 waves). Wp+Wsc staged in LDS once per block.
// A is read via the SCALAR path: node index uniformized with readfirstlane
// -> s_load_dwordx16 of A[m][0..15]; FMAs use SGPR A-operand + VGPR W-operand.
// This removes the A-broadcast LDS replication (128KB delivered per node in
// the old scheme) AND the per-node W global re-stream. Out row staged in a
// correctly-sized 4KB/wave LDS slot (round-5 bug: slot was 2KB) -> 4 coalesced
// float4 stores. LDS 72KB -> 2 blocks/CU = 16 waves/CU.
__global__ __launch_bounds__(512) void k_xform2(
    const float* __restrict__ feat, const float4* __restrict__ A4,
    const float4* __restrict__ Wp, const float* __restrict__ Wsc,
    float* __restrict__ out)
{
  __shared__ __align__(16) float4 sWp[2048];      // 32 KB
  __shared__ float sWs[2048];                     // 8 KB
  __shared__ __align__(16) float sOut[8][1024];   // 32 KB: 4KB out slot/wave

  const int tid = threadIdx.x, wv = tid>>6, lane = tid&63;
  for (int i=tid; i<2048; i+=512){ sWp[i]=Wp[i]; sWs[i]=Wsc[i]; }
  __syncthreads();                                 // once per block

  const int wg = blockIdx.x*8 + wv;                // global wave id, 0..8191
  const float S = 0.17677669529663687f;            // 1/sqrt(32)
  const float S8 = S*0.125f;                       // edge terms carry /DENOM
  const float* Af = (const float*)A4;

  for (int n0 = wg; n0 < NN; n0 += 8192){
    const int nu = __builtin_amdgcn_readfirstlane(n0);   // provably uniform
    const float* An = Af + (size_t)nu*512;               // -> s_load path
    const float* fn = feat + (size_t)nu*32;              // -> s_load path

    float oa[16];
    #pragma unroll
    for (int k=0;k<16;++k) oa[k]=0.f;
    float osc = 0.f;

    #pragma unroll 4
    for (int m=0; m<32; ++m){
      float a[16];
      #pragma unroll
      for (int k=0;k<16;++k) a[k] = An[m*16+k];    // s_load_dwordx16
      float4 wq = sWp[m*64 + lane];                // LDS b128, conflict-free
      float  w4 = sWs[m*64 + lane];
      float fsm = fn[m];                           // s_load
      oa[0] += a[0]*wq.x;
      oa[1] += a[1]*wq.y; oa[2] += a[2]*wq.y; oa[3] += a[3]*wq.y;
      oa[4] += a[4]*wq.z; oa[5] += a[5]*wq.z; oa[6] += a[6]*wq.z;
      oa[7] += a[7]*wq.z; oa[8] += a[8]*wq.z;
      oa[9] += a[9]*wq.w; oa[10]+= a[10]*wq.w; oa[11]+= a[11]*wq.w;
      oa[12]+= a[12]*wq.w; oa[13]+= a[13]*wq.w; oa[14]+= a[14]*wq.w;
      oa[15]+= a[15]*wq.w;
      osc += fsm*w4;
    }

    // stage out row (1024 floats fits the 4KB slot), then coalesced stores
    float* ol = &sOut[wv][0];
    ol[lane] = oa[0]*S8 + osc*S;
    #pragma unroll
    for (int i=0;i<3;++i) ol[64  + lane*3 + i] = oa[1+i]*S8;
    #pragma unroll
    for (int i=0;i<5;++i) ol[256 + lane*5 + i] = oa[4+i]*S8;
    #pragma unroll
    for (int i=0;i<7;++i) ol[576 + lane*7 + i] = oa[9+i]*S8;
    asm volatile("s_waitcnt lgkmcnt(0)" ::: "memory");

    float4* o4 = (float4*)(out + (size_t)nu*1024);
    const float4* s4 = (const float4*)&sOut[wv][0];
    #pragma unroll
    for (int i=0;i<4;++i) o4[i*64 + lane] = s4[i*64 + lane];
    // per-wave in-order LDS pipe: next iter's ds_writes can't pass these
    // ds_reads; stores consume registers, so no global/LDS hazard.
  }
}

extern "C" void kernel_launch(void* const* d_in, const int* in_sizes, int n_in,
                              void* d_out, int out_size, void* d_ws, size_t ws_size,
                              hipStream_t stream) {
  const float* pos  = (const float*)d_in[0];
  const float* feat = (const float*)d_in[1];
  const float* W0   = (const float*)d_in[2];
  const float* W1   = (const float*)d_in[3];
  const float* W2   = (const float*)d_in[4];
  const float* W3   = (const float*)d_in[5];
  const float* Wsc  = (const float*)d_in[6];
  const int*  snd   = (const int*)d_in[7];
  const int*  rcv   = (const int*)d_in[8];
  float* out = (float*)d_out;

  int* ws      = (int*)d_ws;
  int* cnt     = ws;            // 50000
  int* offs    = ws + 50000;    // 50000
  int* cursor  = ws + 100000;   // 50000
  int* bsum    = ws + 150000;   // 256
  int* csr_snd = ws + 150272;   // 400000  (ints end at 550272; 16B aligned)
  float4* Wp   = (float4*)(ws + 550272);          // 2048 float4 = 32 KB
  float4* A4   = (float4*)(ws + 558464);          // 50000*128 float4 = 102.4 MB

  hipMemsetAsync(cnt, 0, NN*sizeof(int), stream);
  k_hist   <<<(NE+255)/256, 256, 0, stream>>>(rcv, cnt);
  k_scanA  <<<SCAN_NB, 256, 0, stream>>>(cnt, bsum);
  k_scanB  <<<1, 256, 0, stream>>>(bsum);
  k_scanC  <<<SCAN_NB, 256, 0, stream>>>(cnt, bsum, offs, cursor);
  k_scatter<<<(NE+255)/256, 256, 0, stream>>>(rcv, snd, cursor, csr_snd);
  k_prepW  <<<8, 256, 0, stream>>>(W0, W1, W2, W3, Wp);
  k_aggr2  <<<25000, 128, 0, stream>>>(pos, feat, offs, cnt, csr_snd, A4);
  k_xform2 <<<1024, 512, 0, stream>>>(feat, A4, Wp, Wsc, out);
}

// Round 7
// 388.627 us; speedup vs baseline: 1.0973x; 1.0973x over previous
//
#include <hip/hip_runtime.h>

#define NN 50000
#define NE 400000
#define SCAN_NB 196   // ceil(50000/256)

__global__ void k_hist(const int* __restrict__ rcv, int* __restrict__ cnt){
  int e = blockIdx.x*256 + threadIdx.x;
  if (e < NE) atomicAdd(&cnt[rcv[e]], 1);
}

__global__ void k_scanA(const int* __restrict__ cnt, int* __restrict__ bsum){
  __shared__ int sh[256];
  int i = blockIdx.x*256 + threadIdx.x;
  int v = (i < NN) ? cnt[i] : 0;
  sh[threadIdx.x] = v; __syncthreads();
  for (int off=128; off>0; off>>=1){
    if (threadIdx.x < off) sh[threadIdx.x] += sh[threadIdx.x+off];
    __syncthreads();
  }
  if (threadIdx.x==0) bsum[blockIdx.x] = sh[0];
}

__global__ void k_scanB(int* __restrict__ bsum){
  __shared__ int sh[256];
  int t = threadIdx.x;
  int v = (t < SCAN_NB) ? bsum[t] : 0;
  sh[t] = v; __syncthreads();
  for (int off=1; off<256; off<<=1){
    int x = (t>=off)? sh[t-off] : 0;
    __syncthreads();
    sh[t] += x;
    __syncthreads();
  }
  if (t < SCAN_NB) bsum[t] = sh[t] - v;   // exclusive
}

__global__ void k_scanC(const int* __restrict__ cnt, const int* __restrict__ bsum,
                        int* __restrict__ offs, int* __restrict__ cursor){
  __shared__ int sh[256];
  int t = threadIdx.x;
  int i = blockIdx.x*256 + t;
  int v = (i < NN) ? cnt[i] : 0;
  sh[t] = v; __syncthreads();
  for (int off=1; off<256; off<<=1){
    int x = (t>=off)? sh[t-off] : 0;
    __syncthreads();
    sh[t] += x;
    __syncthreads();
  }
  int excl = sh[t] - v + bsum[blockIdx.x];
  if (i < NN){ offs[i] = excl; cursor[i] = excl; }
}

__global__ void k_scatter(const int* __restrict__ rcv, const int* __restrict__ snd,
                          int* __restrict__ cursor, int* __restrict__ csr_snd){
  int e = blockIdx.x*256 + threadIdx.x;
  if (e < NE){
    int p = atomicAdd(&cursor[rcv[e]], 1);
    csr_snd[p] = snd[e];
  }
}

// Pack W0..W3 into float4 table: Wp[m*64+t] = {W0,W1,W2,W3}[m][t]
__global__ void k_prepW(const float* __restrict__ W0, const float* __restrict__ W1,
                        const float* __restrict__ W2, const float* __restrict__ W3,
                        float4* __restrict__ Wp){
  int i = blockIdx.x*256 + threadIdx.x;   // 0..2047
  if (i < 2048) Wp[i] = make_float4(W0[i], W1[i], W2[i], W3[i]);
}

// Fused wave-per-2-nodes kernel, NO block barriers, NO A materialization.
//  edge phase (per node): SH staged in LDS (80B/lane pad -> conflict-free),
//    acc[nn][j] = A[m=lane&31][(lane>>5)*8+j] accumulated in VGPRs.
//  transform: A values pulled via v_readlane (lane crossbar, VALU pipe) ->
//    SGPR operand of v_fmac. NO LDS A-broadcast (round-4's 172us LDS bound),
//    NO SMEM A-chain (round-6's 150us latency bound). W streamed from global
//    once per wave-pair of nodes (halved vs per-node).
//  store: out row staged in per-wave LDS slot -> 4 coalesced float4 stores
//    (full 64B lines; round-3 proved scattered stores cost 3x write amp).
__global__ __launch_bounds__(256) void k_main(
    const float* __restrict__ pos, const float* __restrict__ feat,
    const float4* __restrict__ Wp, const float* __restrict__ Wsc,
    const int* __restrict__ offs, const int* __restrict__ cnt,
    const int* __restrict__ csr_snd, float* __restrict__ out)
{
  __shared__ __align__(16) float smS[4][1280];   // 20.5 KB, 80B/lane slots

  const int tid = threadIdx.x, wv = tid>>6, lane = tid&63;
  const int ml = lane&31, hh = lane>>5;
  const int nb = blockIdx.x*8 + wv*2;       // 6250*8 == 50000, 2 nodes/wave

  const float SC3=1.7320508f, SC5=2.236068f, SC7=2.6457513f, SC15=3.8729833f,
              SC42=6.4807407f, SC70=8.3666003f, SC105=10.246951f;

  float acc[2][8];
  #pragma unroll
  for (int nn=0;nn<2;++nn)
    #pragma unroll
    for (int j=0;j<8;++j) acc[nn][j]=0.f;

  // ---- edge phase: two nodes sequentially ----
  #pragma unroll
  for (int nn=0; nn<2; ++nn){
    const int n = nb + nn;
    const float pnx=pos[n*3], pny=pos[n*3+1], pnz=pos[n*3+2];
    const int start = offs[n], deg = cnt[n];
    const int nch = (deg+63)>>6;
    for (int c=0; c<nch; ++c){
      const int base = c<<6;
      int cn = deg - base; cn = (cn>64)?64:cn;   // >=1 inside loop
      int sE = 0;
      if (lane < cn){
        sE = csr_snd[start+base+lane];
        float rx = pnx - pos[sE*3];
        float ry = pny - pos[sE*3+1];
        float rz = pnz - pos[sE*3+2];
        float r = sqrtf(rx*rx+ry*ry+rz*rz);
        float inv = 1.0f/fmaxf(r,1e-12f);
        float x=rx*inv, y=ry*inv, z=rz*inv;
        float x2=x*x, y2=y*y, z2=z*z;
        float s1=SC3*x, s2=SC3*y, s3=SC3*z;
        float s4=SC15*x*y, s5=SC15*y*z, s6=0.5f*SC5*(3.f*z2-1.f), s7=SC15*x*z;
        float s8=0.5f*SC15*(x2-y2);
        float s9 =0.25f*SC70*y*(3.f*x2-y2);
        float s10=SC105*x*y*z;
        float s11=0.25f*SC42*y*(5.f*z2-1.f);
        float s12=0.5f*SC7*z*(5.f*z2-3.f);
        float s13=0.25f*SC42*x*(5.f*z2-1.f);
        float s14=0.5f*SC105*z*(x2-y2);
        float s15=0.25f*SC70*x*(x2-3.f*y2);
        float4* wp = (float4*)&smS[wv][lane*20];  // 80B slot: all banks covered
        wp[0] = make_float4(1.0f,s1,s2,s3);
        wp[1] = make_float4(s4,s5,s6,s7);
        wp[2] = make_float4(s8,s9,s10,s11);
        wp[3] = make_float4(s12,s13,s14,s15);
      }
      // same-wave LDS producer->consumer ordering (waves independent)
      asm volatile("s_waitcnt lgkmcnt(0)" ::: "memory");
      #pragma unroll 8
      for (int it=0; it<cn; ++it){
        int s = __builtin_amdgcn_readlane(sE, it);   // uniform sender id
        float f = feat[(size_t)s*32 + ml];           // 128B segment, L2-hot
        const float4* rp = (const float4*)&smS[wv][it*20 + hh*8];
        float4 q0=rp[0], q1=rp[1];                   // 2-addr broadcast: free
        acc[nn][0]+=f*q0.x; acc[nn][1]+=f*q0.y;
        acc[nn][2]+=f*q0.z; acc[nn][3]+=f*q0.w;
        acc[nn][4]+=f*q1.x; acc[nn][5]+=f*q1.y;
        acc[nn][6]+=f*q1.z; acc[nn][7]+=f*q1.w;
      }
      asm volatile("" ::: "memory");  // reads before next chunk's overwrites
    }
  }

  // ---- transform: A via readlane (crossbar), W from global (L1/L2-hot) ----
  const int n0 = __builtin_amdgcn_readfirstlane(nb);   // provably uniform
  const float* fn0 = feat + (size_t)n0*32;             // -> s_load path
  const float* fn1 = fn0 + 32;

  float oa[2][16];
  #pragma unroll
  for (int nn=0;nn<2;++nn)
    #pragma unroll
    for (int k=0;k<16;++k) oa[nn][k]=0.f;
  float osc0=0.f, osc1=0.f;

  #pragma unroll 4
  for (int m=0; m<32; ++m){
    float4 wq = Wp[m*64 + lane];                 // 1KB coalesced, L1/L2-hot
    float  w4 = Wsc[m*64 + lane];
    float f0 = fn0[m], f1 = fn1[m];              // uniform s_load
    osc0 += f0*w4; osc1 += f1*w4;
    #pragma unroll
    for (int k=0;k<16;++k){
      const int src = m + ((k>>3)<<5);           // holder lane of A[m][k]
      float a0 = __int_as_float(__builtin_amdgcn_readlane(
                   __float_as_int(acc[0][k&7]), src));
      float a1 = __int_as_float(__builtin_amdgcn_readlane(
                   __float_as_int(acc[1][k&7]), src));
      const float w = (k==0)?wq.x : (k<4)?wq.y : (k<9)?wq.z : wq.w;
      oa[0][k] += a0*w;
      oa[1][k] += a1*w;
    }
  }

  // ---- store: per node, stage row in LDS slot -> coalesced float4 ----
  const float S = 0.17677669529663687f;   // 1/sqrt(32)
  const float S8 = S*0.125f;              // edge terms also carry /DENOM
  #pragma unroll
  for (int nn=0; nn<2; ++nn){
    float* ol = &smS[wv][0];              // 1024 floats fit the 1280 slot
    const float osc = nn ? osc1 : osc0;
    ol[lane] = oa[nn][0]*S8 + osc*S;
    #pragma unroll
    for (int i=0;i<3;++i) ol[64  + lane*3 + i] = oa[nn][1+i]*S8;
    #pragma unroll
    for (int i=0;i<5;++i) ol[256 + lane*5 + i] = oa[nn][4+i]*S8;
    #pragma unroll
    for (int i=0;i<7;++i) ol[576 + lane*7 + i] = oa[nn][9+i]*S8;
    asm volatile("s_waitcnt lgkmcnt(0)" ::: "memory");

    float4* o4 = (float4*)(out + (size_t)(n0+nn)*1024);
    const float4* s4 = (const float4*)&smS[wv][0];
    #pragma unroll
    for (int i=0;i<4;++i) o4[i*64 + lane] = s4[i*64 + lane];
    asm volatile("" ::: "memory");        // reads before nn=1's overwrites
  }
}

extern "C" void kernel_launch(void* const* d_in, const int* in_sizes, int n_in,
                              void* d_out, int out_size, void* d_ws, size_t ws_size,
                              hipStream_t stream) {
  const float* pos  = (const float*)d_in[0];
  const float* feat = (const float*)d_in[1];
  const float* W0   = (const float*)d_in[2];
  const float* W1   = (const float*)d_in[3];
  const float* W2   = (const float*)d_in[4];
  const float* W3   = (const float*)d_in[5];
  const float* Wsc  = (const float*)d_in[6];
  const int*  snd   = (const int*)d_in[7];
  const int*  rcv   = (const int*)d_in[8];
  float* out = (float*)d_out;

  int* ws      = (int*)d_ws;
  int* cnt     = ws;            // 50000
  int* offs    = ws + 50000;    // 50000
  int* cursor  = ws + 100000;   // 50000
  int* bsum    = ws + 150000;   // 256
  int* csr_snd = ws + 150272;   // 400000  (ints end at 550272; 16B aligned)
  float4* Wp   = (float4*)(ws + 550272);          // 2048 float4 = 32 KB

  hipMemsetAsync(cnt, 0, NN*sizeof(int), stream);
  k_hist   <<<(NE+255)/256, 256, 0, stream>>>(rcv, cnt);
  k_scanA  <<<SCAN_NB, 256, 0, stream>>>(cnt, bsum);
  k_scanB  <<<1, 256, 0, stream>>>(bsum);
  k_scanC  <<<SCAN_NB, 256, 0, stream>>>(cnt, bsum, offs, cursor);
  k_scatter<<<(NE+255)/256, 256, 0, stream>>>(rcv, snd, cursor, csr_snd);
  k_prepW  <<<8, 256, 0, stream>>>(W0, W1, W2, W3, Wp);
  k_main   <<<6250, 256, 0, stream>>>(pos, feat, Wp, Wsc,
                                      offs, cnt, csr_snd, out);
}